// Round 4
// baseline (280.960 us; speedup 1.0000x reference)
//
#include <hip/hip_runtime.h>
#include <math.h>

// Problem constants (fixed by the reference setup_inputs).
#define N 8192
#define D 64
#define C 100
#define T 30
#define GSTRIDE 32   // padded leading dim of per-class Gram rows
#define ZROWS 32     // z0 rows padded 30 -> 32 for MFMA u-tiles
#define WSTRIDE 20   // per-wave transpose row stride (16 u's + 4 pad)
#define SB 16        // epilogue samples per block

static constexpr float D_LOG_2PI      = 117.62413225019811f; // D * log(2*pi)
static constexpr float EV_BUDGET_F    = 80.992775903017304f; // 0.5 * D * log(4*pi)
static constexpr float LOG_EV_CLAMP_F = 10.0f;

typedef __attribute__((ext_vector_type(8))) short short8x;   // 8 x bf16 bits
typedef __attribute__((ext_vector_type(4))) float floatx4;   // MFMA C/D frag

static __device__ __forceinline__ unsigned short f2bf(float f) {
    __bf16 h = (__bf16)f;                       // RNE convert
    return __builtin_bit_cast(unsigned short, h);
}

// ---------------------------------------------------------------------------
// Kernel X: x -> bf16 (once, not per-class) and q0[n] = ||x_n||^2.
// 256 thr = 32 rows x 8 threads; fully coalesced; width-8 shuffle reduce.
// ---------------------------------------------------------------------------
__global__ __launch_bounds__(256) void xprep_kernel(
        const float* __restrict__ x,
        unsigned short* __restrict__ xbf,
        float* __restrict__ q0) {
    const int r = blockIdx.x * 32 + (threadIdx.x >> 3);  // sample row
    const int e = threadIdx.x & 7;                       // 8-float chunk
    const float4* xp = (const float4*)(x + (size_t)r * D + e * 8);
    const float4 a = xp[0], b = xp[1];
    short8x o;
    o[0] = f2bf(a.x); o[1] = f2bf(a.y); o[2] = f2bf(a.z); o[3] = f2bf(a.w);
    o[4] = f2bf(b.x); o[5] = f2bf(b.y); o[6] = f2bf(b.z); o[7] = f2bf(b.w);
    *(short8x*)(xbf + (size_t)r * D + e * 8) = o;
    float q = a.x*a.x + a.y*a.y + a.z*a.z + a.w*a.w
            + b.x*b.x + b.y*b.y + b.z*b.z + b.w*b.w;
    q += __shfl_xor(q, 4, 8);
    q += __shfl_xor(q, 2, 8);
    q += __shfl_xor(q, 1, 8);
    if (e == 0) q0[r] = q;
}

// ---------------------------------------------------------------------------
// Kernel P: per-class precompute (Gram, softplus params, bf16 z0).
// ---------------------------------------------------------------------------
__global__ void prep_kernel(const float* __restrict__ z0,
                            const float* __restrict__ ap,
                            const float* __restrict__ bp,
                            float* __restrict__ Gp,
                            float* __restrict__ alphas,
                            float* __restrict__ betas,
                            unsigned short* __restrict__ z0bf) {
    const int c = blockIdx.x;
    __shared__ float z0s[T * D];
    for (int i = threadIdx.x; i < T * D; i += blockDim.x)
        z0s[i] = z0[c * T * D + i];
    __syncthreads();

    for (int idx = threadIdx.x; idx < T * T; idx += blockDim.x) {
        const int u = idx / T, v = idx % T;
        float s = 0.0f;
        #pragma unroll
        for (int d = 0; d < D; ++d)
            s = fmaf(z0s[u * D + d], z0s[v * D + d], s);
        Gp[(size_t)c * T * GSTRIDE + u * GSTRIDE + v] = s;
    }

    for (int i = threadIdx.x; i < ZROWS * D; i += blockDim.x) {
        const int u = i >> 6;
        z0bf[(size_t)c * ZROWS * D + i] = f2bf(u < T ? z0s[u * D + (i & 63)] : 0.0f);
    }

    if (threadIdx.x < T) {
        const float a = ap[c * T + threadIdx.x];
        const float b = bp[c * T + threadIdx.x];
        const float spa = fmaxf(a, 0.0f) + log1pf(expf(-fabsf(a)));
        const float spb = fmaxf(b, 0.0f) + log1pf(expf(-fabsf(b)));
        alphas[c * T + threadIdx.x] = spa;
        betas[c * T + threadIdx.x]  = -spa + spb;
    }
}

// ---------------------------------------------------------------------------
// Kernel A: flow. Phase 1 = MFMA [32u x 64n]/wave; per-wave 2-pass LDS
// transpose (no barrier: wave-lockstep). Phase 2 = Gram-trick recurrence;
// G/alpha/beta read from LDS via BROADCAST ds_reads (the R3 inflation was
// non-scalarized per-lane global loads of G — this kills it by construction).
// ---------------------------------------------------------------------------
__global__ __launch_bounds__(256, 6) void flow_kernel(
        const unsigned short* __restrict__ xbf,
        const float* __restrict__ q0g,
        const unsigned short* __restrict__ z0bf,
        const float* __restrict__ Gp,
        const float* __restrict__ alphas,
        const float* __restrict__ betas,
        float* __restrict__ lp) {
    const int c    = blockIdx.y;
    const int wv   = threadIdx.x >> 6;
    const int ln   = threadIdx.x & 63;
    const int col  = ln & 15;
    const int quad = ln >> 4;
    const int nb   = blockIdx.x * 256 + wv * 64;
    const int n    = nb + ln;

    __shared__ float Gs[T * GSTRIDE];        // 3840 B
    __shared__ float ab[64];                 // alpha[0..29] | beta at +32
    __shared__ float wlds[4][64 * WSTRIDE];  // 20480 B

    for (int i = threadIdx.x; i < T * GSTRIDE; i += 256)
        Gs[i] = Gp[(size_t)c * T * GSTRIDE + i];
    if (threadIdx.x < T) ab[threadIdx.x] = alphas[c * T + threadIdx.x];
    else if (threadIdx.x >= 32 && threadIdx.x < 32 + T)
        ab[threadIdx.x] = betas[c * T + (threadIdx.x - 32)];
    __syncthreads();

    // ---- Phase 1: w[u][n] = z0 . x via MFMA (A = z0 rows, B = x cols) ----
    const unsigned short* zb = z0bf + (size_t)c * ZROWS * D;
    short8x A[2][2];
    #pragma unroll
    for (int mu = 0; mu < 2; ++mu)
        #pragma unroll
        for (int kc = 0; kc < 2; ++kc)
            A[mu][kc] = *(const short8x*)(zb + (mu * 16 + col) * D + kc * 32 + quad * 8);

    floatx4 acc[2][4];
    #pragma unroll
    for (int mu = 0; mu < 2; ++mu)
        #pragma unroll
        for (int nt = 0; nt < 4; ++nt)
            acc[mu][nt] = (floatx4)(0.0f);

    #pragma unroll
    for (int nt = 0; nt < 4; ++nt) {
        #pragma unroll
        for (int kc = 0; kc < 2; ++kc) {
            const short8x B = *(const short8x*)(
                xbf + (size_t)(nb + nt * 16 + col) * D + kc * 32 + quad * 8);
            acc[0][nt] = __builtin_amdgcn_mfma_f32_16x16x32_bf16(A[0][kc], B, acc[0][nt], 0, 0, 0);
            acc[1][nt] = __builtin_amdgcn_mfma_f32_16x16x32_bf16(A[1][kc], B, acc[1][nt], 0, 0, 0);
        }
    }

    const float q_init = q0g[n];   // precomputed fp32 ||x||^2 (coalesced)

    // ---- per-wave transpose, two passes over the same 20-stride buffer ----
    float w[ZROWS];
    #pragma unroll
    for (int mu = 0; mu < 2; ++mu) {
        #pragma unroll
        for (int nt = 0; nt < 4; ++nt)
            *(floatx4*)&wlds[wv][(nt * 16 + col) * WSTRIDE + quad * 4] = acc[mu][nt];
        // same-wave producer/consumer: lockstep, compiler orders via aliasing
        #pragma unroll
        for (int j = 0; j < 4; ++j) {
            const float4 t = *(const float4*)&wlds[wv][ln * WSTRIDE + j * 4];
            w[mu * 16 + 4 * j + 0] = t.x; w[mu * 16 + 4 * j + 1] = t.y;
            w[mu * 16 + 4 * j + 2] = t.z; w[mu * 16 + 4 * j + 3] = t.w;
        }
    }

    // ---- Phase 2 (verified): true w_t[u] = P*w[u]; q = ||z_t||^2 ----
    float q    = q_init;
    float P    = 1.0f;
    float prod = 1.0f;
    float ld   = 0.0f;
    #pragma unroll
    for (int t = 0; t < T; ++t) {
        const float Gtt   = Gs[t * GSTRIDE + t];   // broadcast ds_read
        const float alpha = ab[t];
        const float beta  = ab[32 + t];
        const float wt    = P * w[t];
        float r2 = fmaf(-2.0f, wt, q) + Gtt;
        r2 = fmaxf(r2, 0.0f);
        const float r  = __builtin_amdgcn_sqrtf(r2);
        const float h  = __builtin_amdgcn_rcpf(alpha + r);
        const float bh = beta * h;
        const float f  = 1.0f + bh;
        // det factor: f^63 * (1 + bh*alpha*h);  (1 - h*r == alpha*h)
        const float f2 = f * f, f4 = f2 * f2, f8 = f4 * f4;
        const float f16 = f8 * f8, f32v = f16 * f16;
        float p = f32v * f16; p *= f8; p *= f4; p *= f2; p *= f;  // f^63
        p *= fmaf(bh * alpha, h, 1.0f);
        prod *= p;
        if ((t % 6) == 5) { ld += __logf(prod); prod = 1.0f; }
        // q_{t+1} = f^2 q - 2 f bh wt + bh^2 Gtt
        const float m = bh * f;
        float qn = f2 * q;
        qn = fmaf(m, -2.0f * wt, qn);
        qn = fmaf(bh * bh, Gtt, qn);
        q = qn;
        // scaled-w update, vectorized over aligned 4-blocks; updating u <= t
        // is harmless (those w are already consumed), so no edge masking.
        const float Pn = P * f;
        const float k  = bh * __builtin_amdgcn_rcpf(Pn);
        #pragma unroll
        for (int m4 = 0; m4 < 8; ++m4) {
            if (m4 < (t >> 2)) continue;          // blocks fully in the past
            const float4 g = *(const float4*)&Gs[t * GSTRIDE + 4 * m4];  // broadcast b128
            w[4 * m4 + 0] = fmaf(-k, g.x, w[4 * m4 + 0]);
            w[4 * m4 + 1] = fmaf(-k, g.y, w[4 * m4 + 1]);
            w[4 * m4 + 2] = fmaf(-k, g.z, w[4 * m4 + 2]);
            w[4 * m4 + 3] = fmaf(-k, g.w, w[4 * m4 + 3]);
        }
        P = Pn;
    }
    ld += __logf(prod);

    lp[(size_t)c * N + n] = -0.5f * (D_LOG_2PI + q) + ld;
}

// ---------------------------------------------------------------------------
// Kernel C: epilogue. 512 blocks x 256 thr; 16 samples/block, 16 lanes/sample
// (groups live inside one wave -> width-16 shuffles). lp tile loaded
// COALESCED into LDS (the R3 version gathered lane-stride-32KB). W, x, b,
// log(freq), labels all staged in LDS.
// ---------------------------------------------------------------------------
__global__ __launch_bounds__(256) void epilogue_kernel(
        const float* __restrict__ lp,
        const float* __restrict__ x,
        const float* __restrict__ W,
        const float* __restrict__ b,
        const int* __restrict__ labels,
        const float* __restrict__ freq,
        float* __restrict__ out) {
    const int n0  = blockIdx.x * SB;
    const int tid = threadIdx.x;

    __shared__ float lps[SB][101];   // pad 101: conflict-free strided writes
    __shared__ float xs[SB][65];
    __shared__ float Ws[D * C];      // 25.6 KB
    __shared__ float lf[C];
    __shared__ float bsm[C];
    __shared__ int   lbl[SB];

    for (int i = tid; i < C * SB; i += 256)            // coalesced 16-runs
        lps[i & (SB - 1)][i >> 4] = lp[(size_t)(i >> 4) * N + n0 + (i & (SB - 1))];
    for (int i = tid; i < SB * D; i += 256)            // fully coalesced
        xs[i >> 6][i & 63] = x[(size_t)n0 * D + i];
    for (int i = tid; i < D * C; i += 256)
        Ws[i] = W[i];
    if (tid < C) { lf[tid] = __logf(freq[tid]); bsm[tid] = b[tid]; }
    if (tid < SB) lbl[tid] = labels[n0 + tid];
    __syncthreads();

    const int s = tid >> 4;          // sample in tile (groups of 16 in-wave)
    const int k = tid & 15;          // lane within sample group
    const int n = n0 + s;

    // logits for classes c = k + 16j (<=7 per lane); Ws reads broadcast
    // across the 4 sample-groups of a wave, 16 distinct banks -> conflict-free
    float lgt[7];
    float lm = -INFINITY;
    float vm = -INFINITY, vs = 0.0f;   // online logsumexp partial (lp+lf)
    #pragma unroll
    for (int j = 0; j < 7; ++j) {
        const int c = k + 16 * j;
        if (c < C) {
            float t = bsm[c];
            #pragma unroll
            for (int d = 0; d < D; ++d)
                t = fmaf(xs[s][d], Ws[d * C + c], t);
            lgt[j] = t;
            lm = fmaxf(lm, t);
            const float v = lps[s][c] + lf[c];
            const float m2 = fmaxf(vm, v);
            vs = vs * __expf(vm - m2) + __expf(v - m2);
            vm = m2;
        } else lgt[j] = -INFINITY;
    }

    // combine 16-lane partials: (vm,vs) logsumexp merge + lm max
    #pragma unroll
    for (int off = 8; off >= 1; off >>= 1) {
        const float om = __shfl_xor(vm, off, 16);
        const float os = __shfl_xor(vs, off, 16);
        const float m2 = fmaxf(vm, om);
        vs = vs * __expf(vm - m2) + os * __expf(om - m2);
        vm = m2;
        lm = fmaxf(lm, __shfl_xor(lm, off, 16));
    }
    const float marg = vm + __logf(vs);
    const float ev = __expf(fminf(marg + EV_BUDGET_F, LOG_EV_CLAMP_F));

    float ls = 0.0f;
    #pragma unroll
    for (int j = 0; j < 7; ++j)
        if (k + 16 * j < C) ls += __expf(lgt[j] - lm);
    #pragma unroll
    for (int off = 8; off >= 1; off >>= 1)
        ls += __shfl_xor(ls, off, 16);

    const float inv = ev / ls;
    float* __restrict__ outr = out + (size_t)n * (C + 1);
    #pragma unroll
    for (int j = 0; j < 7; ++j) {
        const int c = k + 16 * j;
        if (c < C) outr[c] = log1pf(__expf(lgt[j] - lm) * inv);  // 16-run coalesced
    }
    if (k == 0) outr[C] = lps[s][lbl[s]];
}

// ---------------------------------------------------------------------------
extern "C" void kernel_launch(void* const* d_in, const int* in_sizes, int n_in,
                              void* d_out, int out_size, void* d_ws, size_t ws_size,
                              hipStream_t stream) {
    const float* x      = (const float*)d_in[0];
    const int*   labels = (const int*)  d_in[1];
    const float* freq   = (const float*)d_in[2];
    const float* z0     = (const float*)d_in[3];
    const float* ap     = (const float*)d_in[4];
    const float* bp     = (const float*)d_in[5];
    const float* W      = (const float*)d_in[6];
    const float* b      = (const float*)d_in[7];
    float* out = (float*)d_out;

    // Workspace: lp[C*N] | Gp[C*T*32] | alpha | beta | z0bf | xbf | q0
    float* ws     = (float*)d_ws;
    float* lp     = ws;
    float* Gp     = lp + (size_t)C * N;
    float* alphas = Gp + (size_t)C * T * GSTRIDE;
    float* betas  = alphas + (size_t)C * T;
    unsigned short* z0bf = (unsigned short*)(betas + (size_t)C * T);
    unsigned short* xbf  = z0bf + (size_t)C * ZROWS * D;
    float* q0     = (float*)(xbf + (size_t)N * D);

    xprep_kernel<<<N / 32, 256, 0, stream>>>(x, xbf, q0);
    prep_kernel<<<C, 256, 0, stream>>>(z0, ap, bp, Gp, alphas, betas, z0bf);
    flow_kernel<<<dim3(N / 256, C), 256, 0, stream>>>(xbf, q0, z0bf, Gp, alphas, betas, lp);
    epilogue_kernel<<<N / SB, 256, 0, stream>>>(lp, x, W, b, labels, freq, out);
}

// Round 5
// 195.348 us; speedup vs baseline: 1.4383x; 1.4383x over previous
//
#include <hip/hip_runtime.h>
#include <math.h>

// Problem constants (fixed by the reference setup_inputs).
#define N 8192
#define D 64
#define C 100
#define T 30
#define GSTRIDE 32   // padded leading dim of per-class Gram rows
#define ZROWS 32     // z0 rows padded 30 -> 32 for MFMA u-tiles
#define WSTRIDE 20   // per-wave transpose row stride (16 u's + 4 pad)
#define SB 16        // epilogue samples per block

static constexpr float D_LOG_2PI      = 117.62413225019811f; // D * log(2*pi)
static constexpr float EV_BUDGET_F    = 80.992775903017304f; // 0.5 * D * log(4*pi)
static constexpr float LOG_EV_CLAMP_F = 10.0f;

typedef __attribute__((ext_vector_type(8))) short short8x;   // 8 x bf16 bits
typedef __attribute__((ext_vector_type(4))) float floatx4;   // MFMA C/D frag

static __device__ __forceinline__ unsigned short f2bf(float f) {
    __bf16 h = (__bf16)f;                       // RNE convert
    return __builtin_bit_cast(unsigned short, h);
}

// ---------------------------------------------------------------------------
// Kernel X: x -> bf16 (once, not per-class) and q0[n] = ||x_n||^2.
// ---------------------------------------------------------------------------
__global__ __launch_bounds__(256) void xprep_kernel(
        const float* __restrict__ x,
        unsigned short* __restrict__ xbf,
        float* __restrict__ q0) {
    const int r = blockIdx.x * 32 + (threadIdx.x >> 3);  // sample row
    const int e = threadIdx.x & 7;                       // 8-float chunk
    const float4* xp = (const float4*)(x + (size_t)r * D + e * 8);
    const float4 a = xp[0], b = xp[1];
    short8x o;
    o[0] = f2bf(a.x); o[1] = f2bf(a.y); o[2] = f2bf(a.z); o[3] = f2bf(a.w);
    o[4] = f2bf(b.x); o[5] = f2bf(b.y); o[6] = f2bf(b.z); o[7] = f2bf(b.w);
    *(short8x*)(xbf + (size_t)r * D + e * 8) = o;
    float q = a.x*a.x + a.y*a.y + a.z*a.z + a.w*a.w
            + b.x*b.x + b.y*b.y + b.z*b.z + b.w*b.w;
    q += __shfl_xor(q, 4, 8);
    q += __shfl_xor(q, 2, 8);
    q += __shfl_xor(q, 1, 8);
    if (e == 0) q0[r] = q;
}

// ---------------------------------------------------------------------------
// Kernel P: per-class precompute (Gram, softplus params, bf16 z0).
// ---------------------------------------------------------------------------
__global__ void prep_kernel(const float* __restrict__ z0,
                            const float* __restrict__ ap,
                            const float* __restrict__ bp,
                            float* __restrict__ Gp,
                            float* __restrict__ alphas,
                            float* __restrict__ betas,
                            unsigned short* __restrict__ z0bf) {
    const int c = blockIdx.x;
    __shared__ float z0s[T * D];
    for (int i = threadIdx.x; i < T * D; i += blockDim.x)
        z0s[i] = z0[c * T * D + i];
    __syncthreads();

    for (int idx = threadIdx.x; idx < T * T; idx += blockDim.x) {
        const int u = idx / T, v = idx % T;
        float s = 0.0f;
        #pragma unroll
        for (int d = 0; d < D; ++d)
            s = fmaf(z0s[u * D + d], z0s[v * D + d], s);
        Gp[(size_t)c * T * GSTRIDE + u * GSTRIDE + v] = s;
    }

    for (int i = threadIdx.x; i < ZROWS * D; i += blockDim.x) {
        const int u = i >> 6;
        z0bf[(size_t)c * ZROWS * D + i] = f2bf(u < T ? z0s[u * D + (i & 63)] : 0.0f);
    }

    if (threadIdx.x < T) {
        const float a = ap[c * T + threadIdx.x];
        const float b = bp[c * T + threadIdx.x];
        const float spa = fmaxf(a, 0.0f) + log1pf(expf(-fabsf(a)));
        const float spb = fmaxf(b, 0.0f) + log1pf(expf(-fabsf(b)));
        alphas[c * T + threadIdx.x] = spa;
        betas[c * T + threadIdx.x]  = -spa + spb;
    }
}

// ---------------------------------------------------------------------------
// Kernel A: flow. Phase 1 = MFMA [32u x 64n]/wave; per-wave LDS transpose.
// Phase 2 = Gram-trick recurrence with G/alpha/beta in LDS (broadcast reads).
// __launch_bounds__(256, 4): R4's (256,6) cut the unified VGPR/AGPR budget
// below the ~92-reg live set -> scratch spill, 814 MB HBM traffic, 3x slower.
// DO NOT raise the min-waves arg on this kernel.
// ---------------------------------------------------------------------------
__global__ __launch_bounds__(256, 4) void flow_kernel(
        const unsigned short* __restrict__ xbf,
        const float* __restrict__ q0g,
        const unsigned short* __restrict__ z0bf,
        const float* __restrict__ Gp,
        const float* __restrict__ alphas,
        const float* __restrict__ betas,
        float* __restrict__ lp) {
    const int c    = blockIdx.y;
    const int wv   = threadIdx.x >> 6;
    const int ln   = threadIdx.x & 63;
    const int col  = ln & 15;
    const int quad = ln >> 4;
    const int nb   = blockIdx.x * 256 + wv * 64;
    const int n    = nb + ln;

    __shared__ float Gs[T * GSTRIDE];        // 3840 B
    __shared__ float ab[64];                 // alpha[0..29] | beta at +32
    __shared__ float wlds[4][64 * WSTRIDE];  // 20480 B

    for (int i = threadIdx.x; i < T * GSTRIDE; i += 256)
        Gs[i] = Gp[(size_t)c * T * GSTRIDE + i];
    if (threadIdx.x < T) ab[threadIdx.x] = alphas[c * T + threadIdx.x];
    else if (threadIdx.x >= 32 && threadIdx.x < 32 + T)
        ab[threadIdx.x] = betas[c * T + (threadIdx.x - 32)];
    __syncthreads();

    // ---- Phase 1: w[u][n] = z0 . x via MFMA (A = z0 rows, B = x cols) ----
    const unsigned short* zb = z0bf + (size_t)c * ZROWS * D;
    short8x A[2][2];
    #pragma unroll
    for (int mu = 0; mu < 2; ++mu)
        #pragma unroll
        for (int kc = 0; kc < 2; ++kc)
            A[mu][kc] = *(const short8x*)(zb + (mu * 16 + col) * D + kc * 32 + quad * 8);

    floatx4 acc[2][4];
    #pragma unroll
    for (int mu = 0; mu < 2; ++mu)
        #pragma unroll
        for (int nt = 0; nt < 4; ++nt)
            acc[mu][nt] = (floatx4)(0.0f);

    #pragma unroll
    for (int nt = 0; nt < 4; ++nt) {
        #pragma unroll
        for (int kc = 0; kc < 2; ++kc) {
            const short8x B = *(const short8x*)(
                xbf + (size_t)(nb + nt * 16 + col) * D + kc * 32 + quad * 8);
            acc[0][nt] = __builtin_amdgcn_mfma_f32_16x16x32_bf16(A[0][kc], B, acc[0][nt], 0, 0, 0);
            acc[1][nt] = __builtin_amdgcn_mfma_f32_16x16x32_bf16(A[1][kc], B, acc[1][nt], 0, 0, 0);
        }
    }

    const float q_init = q0g[n];   // precomputed fp32 ||x||^2 (coalesced)

    // ---- per-wave transpose, two passes over the same 20-stride buffer ----
    float w[ZROWS];
    #pragma unroll
    for (int mu = 0; mu < 2; ++mu) {
        #pragma unroll
        for (int nt = 0; nt < 4; ++nt)
            *(floatx4*)&wlds[wv][(nt * 16 + col) * WSTRIDE + quad * 4] = acc[mu][nt];
        // same-wave producer/consumer: lockstep, compiler orders via aliasing
        #pragma unroll
        for (int j = 0; j < 4; ++j) {
            const float4 t = *(const float4*)&wlds[wv][ln * WSTRIDE + j * 4];
            w[mu * 16 + 4 * j + 0] = t.x; w[mu * 16 + 4 * j + 1] = t.y;
            w[mu * 16 + 4 * j + 2] = t.z; w[mu * 16 + 4 * j + 3] = t.w;
        }
    }

    // ---- Phase 2 (verified): true w_t[u] = P*w[u]; q = ||z_t||^2 ----
    float q    = q_init;
    float P    = 1.0f;
    float prod = 1.0f;
    float ld   = 0.0f;
    #pragma unroll
    for (int t = 0; t < T; ++t) {
        const float Gtt   = Gs[t * GSTRIDE + t];   // broadcast ds_read
        const float alpha = ab[t];
        const float beta  = ab[32 + t];
        const float wt    = P * w[t];
        float r2 = fmaf(-2.0f, wt, q) + Gtt;
        r2 = fmaxf(r2, 0.0f);
        const float r  = __builtin_amdgcn_sqrtf(r2);
        const float h  = __builtin_amdgcn_rcpf(alpha + r);
        const float bh = beta * h;
        const float f  = 1.0f + bh;
        // det factor: f^63 * (1 + bh*alpha*h);  (1 - h*r == alpha*h)
        const float f2 = f * f, f4 = f2 * f2, f8 = f4 * f4;
        const float f16 = f8 * f8, f32v = f16 * f16;
        float p = f32v * f16; p *= f8; p *= f4; p *= f2; p *= f;  // f^63
        p *= fmaf(bh * alpha, h, 1.0f);
        prod *= p;
        if ((t % 6) == 5) { ld += __logf(prod); prod = 1.0f; }
        // q_{t+1} = f^2 q - 2 f bh wt + bh^2 Gtt
        const float m = bh * f;
        float qn = f2 * q;
        qn = fmaf(m, -2.0f * wt, qn);
        qn = fmaf(bh * bh, Gtt, qn);
        q = qn;
        // scaled-w update, vectorized over aligned 4-blocks; updating u <= t
        // is harmless (those w are already consumed), so no edge masking.
        const float Pn = P * f;
        const float k  = bh * __builtin_amdgcn_rcpf(Pn);
        #pragma unroll
        for (int m4 = 0; m4 < 8; ++m4) {
            if (m4 < (t >> 2)) continue;          // blocks fully in the past
            const float4 g = *(const float4*)&Gs[t * GSTRIDE + 4 * m4];  // broadcast b128
            w[4 * m4 + 0] = fmaf(-k, g.x, w[4 * m4 + 0]);
            w[4 * m4 + 1] = fmaf(-k, g.y, w[4 * m4 + 1]);
            w[4 * m4 + 2] = fmaf(-k, g.z, w[4 * m4 + 2]);
            w[4 * m4 + 3] = fmaf(-k, g.w, w[4 * m4 + 3]);
        }
        P = Pn;
    }
    ld += __logf(prod);

    lp[(size_t)c * N + n] = -0.5f * (D_LOG_2PI + q) + ld;
}

// ---------------------------------------------------------------------------
// Kernel C: epilogue. 512 blocks x 256 thr; 16 samples/block, 16 lanes/sample
// (groups live inside one wave -> width-16 shuffles). lp tile coalesced into
// LDS; W, x, b, log(freq), labels staged in LDS.
// ---------------------------------------------------------------------------
__global__ __launch_bounds__(256) void epilogue_kernel(
        const float* __restrict__ lp,
        const float* __restrict__ x,
        const float* __restrict__ W,
        const float* __restrict__ b,
        const int* __restrict__ labels,
        const float* __restrict__ freq,
        float* __restrict__ out) {
    const int n0  = blockIdx.x * SB;
    const int tid = threadIdx.x;

    __shared__ float lps[SB][101];   // pad 101: conflict-free strided writes
    __shared__ float xs[SB][65];
    __shared__ float Ws[D * C];      // 25.6 KB
    __shared__ float lf[C];
    __shared__ float bsm[C];
    __shared__ int   lbl[SB];

    for (int i = tid; i < C * SB; i += 256)            // coalesced 16-runs
        lps[i & (SB - 1)][i >> 4] = lp[(size_t)(i >> 4) * N + n0 + (i & (SB - 1))];
    for (int i = tid; i < SB * D; i += 256)            // fully coalesced
        xs[i >> 6][i & 63] = x[(size_t)n0 * D + i];
    for (int i = tid; i < D * C; i += 256)
        Ws[i] = W[i];
    if (tid < C) { lf[tid] = __logf(freq[tid]); bsm[tid] = b[tid]; }
    if (tid < SB) lbl[tid] = labels[n0 + tid];
    __syncthreads();

    const int s = tid >> 4;          // sample in tile (groups of 16 in-wave)
    const int k = tid & 15;          // lane within sample group
    const int n = n0 + s;

    float lgt[7];
    float lm = -INFINITY;
    float vm = -INFINITY, vs = 0.0f;   // online logsumexp partial (lp+lf)
    #pragma unroll
    for (int j = 0; j < 7; ++j) {
        const int c = k + 16 * j;
        if (c < C) {
            float t = bsm[c];
            #pragma unroll
            for (int d = 0; d < D; ++d)
                t = fmaf(xs[s][d], Ws[d * C + c], t);
            lgt[j] = t;
            lm = fmaxf(lm, t);
            const float v = lps[s][c] + lf[c];
            const float m2 = fmaxf(vm, v);
            vs = vs * __expf(vm - m2) + __expf(v - m2);
            vm = m2;
        } else lgt[j] = -INFINITY;
    }

    #pragma unroll
    for (int off = 8; off >= 1; off >>= 1) {
        const float om = __shfl_xor(vm, off, 16);
        const float os = __shfl_xor(vs, off, 16);
        const float m2 = fmaxf(vm, om);
        vs = vs * __expf(vm - m2) + os * __expf(om - m2);
        vm = m2;
        lm = fmaxf(lm, __shfl_xor(lm, off, 16));
    }
    const float marg = vm + __logf(vs);
    const float ev = __expf(fminf(marg + EV_BUDGET_F, LOG_EV_CLAMP_F));

    float ls = 0.0f;
    #pragma unroll
    for (int j = 0; j < 7; ++j)
        if (k + 16 * j < C) ls += __expf(lgt[j] - lm);
    #pragma unroll
    for (int off = 8; off >= 1; off >>= 1)
        ls += __shfl_xor(ls, off, 16);

    const float inv = ev / ls;
    float* __restrict__ outr = out + (size_t)n * (C + 1);
    #pragma unroll
    for (int j = 0; j < 7; ++j) {
        const int c = k + 16 * j;
        if (c < C) outr[c] = log1pf(__expf(lgt[j] - lm) * inv);  // 16-run coalesced
    }
    if (k == 0) outr[C] = lps[s][lbl[s]];
}

// ---------------------------------------------------------------------------
extern "C" void kernel_launch(void* const* d_in, const int* in_sizes, int n_in,
                              void* d_out, int out_size, void* d_ws, size_t ws_size,
                              hipStream_t stream) {
    const float* x      = (const float*)d_in[0];
    const int*   labels = (const int*)  d_in[1];
    const float* freq   = (const float*)d_in[2];
    const float* z0     = (const float*)d_in[3];
    const float* ap     = (const float*)d_in[4];
    const float* bp     = (const float*)d_in[5];
    const float* W      = (const float*)d_in[6];
    const float* b      = (const float*)d_in[7];
    float* out = (float*)d_out;

    // Workspace: lp[C*N] | Gp[C*T*32] | alpha | beta | z0bf | xbf | q0
    float* ws     = (float*)d_ws;
    float* lp     = ws;
    float* Gp     = lp + (size_t)C * N;
    float* alphas = Gp + (size_t)C * T * GSTRIDE;
    float* betas  = alphas + (size_t)C * T;
    unsigned short* z0bf = (unsigned short*)(betas + (size_t)C * T);
    unsigned short* xbf  = z0bf + (size_t)C * ZROWS * D;
    float* q0     = (float*)(xbf + (size_t)N * D);

    xprep_kernel<<<N / 32, 256, 0, stream>>>(x, xbf, q0);
    prep_kernel<<<C, 256, 0, stream>>>(z0, ap, bp, Gp, alphas, betas, z0bf);
    flow_kernel<<<dim3(N / 256, C), 256, 0, stream>>>(xbf, q0, z0bf, Gp, alphas, betas, lp);
    epilogue_kernel<<<N / SB, 256, 0, stream>>>(lp, x, W, b, labels, freq, out);
}